// Round 10
// baseline (570.982 us; speedup 1.0000x reference)
//
#include <hip/hip_runtime.h>

#define TT 256
#define II 30
#define HH 128
#define TB 8            // samples per WG -> 512 WGs, 2 WGs/CU
#define NR 16           // MFMA A-tile rows (samples padded with zeros)
#define HROWF 136       // f16 stride for h panel rows (272B)
#define XROWF 40        // f16 stride for x panel rows (80B)
#define XTT 16          // timesteps per staged window
#define XPANEL (XTT * NR * XROWF)   // 10240 f16 per buffer

typedef _Float16 half8 __attribute__((ext_vector_type(8)));
typedef float f32x4 __attribute__((ext_vector_type(4)));

#if __has_builtin(__builtin_amdgcn_exp2f)
#define EXP2(x) __builtin_amdgcn_exp2f(x)
#else
#define EXP2(x) exp2f(x)
#endif
#define RCP(x) __builtin_amdgcn_rcpf(x)

#define L2E 1.44269504089f
#define TWO_L2E 2.88539008177f

__global__ __launch_bounds__(512, 4)
void lstm_mfma(const float* __restrict__ x,
               const float* __restrict__ W_ih,
               const float* __restrict__ W_hh,
               const float* __restrict__ b_ih,
               const float* __restrict__ b_hh,
               const float* __restrict__ W0,
               const float* __restrict__ b0v,
               const float* __restrict__ W1,
               const float* __restrict__ b1v,
               float* __restrict__ out)
{
  __shared__ __align__(16) _Float16 Hb[2][NR * HROWF];
  __shared__ __align__(16) _Float16 Xp[2][XPANEL];
  __shared__ float y0ls[TB * 132];

  const int tid = threadIdx.x;
  const int bbase = blockIdx.x * TB;
  const int wv = tid >> 6;      // wave 0..7
  const int lane = tid & 63;
  const int col = lane & 15;    // A-row (sample) / D-col (unit)
  const int grp = lane >> 4;    // k-slot group / D-row block

  // ---- B-fragments (pre-scaled for exp2 gates); wave wv owns units wv*16+col,
  // lane holds i,f,g,o preacts of the SAME unit -> gate math lane-local ----
  half8 bf[4][5];
  float bias[4];
  #pragma unroll
  for (int g = 0; g < 4; ++g) {
    const float sc = (g == 2) ? TWO_L2E : L2E;
    const int n = g * 128 + wv * 16 + col;
    #pragma unroll
    for (int ks = 0; ks < 4; ++ks) {
      const float4 p = *reinterpret_cast<const float4*>(W_hh + n * HH + ks * 32 + grp * 8);
      const float4 q = *reinterpret_cast<const float4*>(W_hh + n * HH + ks * 32 + grp * 8 + 4);
      bf[g][ks] = (half8){(_Float16)(p.x * sc), (_Float16)(p.y * sc),
                          (_Float16)(p.z * sc), (_Float16)(p.w * sc),
                          (_Float16)(q.x * sc), (_Float16)(q.y * sc),
                          (_Float16)(q.z * sc), (_Float16)(q.w * sc)};
    }
    {
      float v[8];
      #pragma unroll
      for (int j = 0; j < 8; ++j) {
        const int cc = grp * 8 + j;
        v[j] = (cc < II) ? W_ih[n * II + cc] * sc : 0.0f;
      }
      bf[g][4] = (half8){(_Float16)v[0], (_Float16)v[1], (_Float16)v[2], (_Float16)v[3],
                         (_Float16)v[4], (_Float16)v[5], (_Float16)v[6], (_Float16)v[7]};
    }
    bias[g] = (b_ih[n] + b_hh[n]) * sc;
  }

  // ---- x stager: 240 threads x 16 consecutive floats per window ----
  const bool stg = (tid < 240);
  const int sS = stg ? (tid / 30) : 7;   // 0..7
  const int qS = tid % 30;
  const int g0 = qS * 16;
  const int tt0 = g0 / 30;
  const int i00 = g0 % 30;
  const float* wbase = x + (size_t)(bbase + sS) * (TT * II);

  float4 xr0, xr1, xr2, xr3;
  auto xload = [&](int win) {
    if (!stg) return;
    const float* p = wbase + win * (XTT * II) + g0;   // 64B-aligned
    xr0 = *reinterpret_cast<const float4*>(p);
    xr1 = *reinterpret_cast<const float4*>(p + 4);
    xr2 = *reinterpret_cast<const float4*>(p + 8);
    xr3 = *reinterpret_cast<const float4*>(p + 12);
  };
  auto xwrite = [&](int dstb) {
    if (!stg) return;
    _Float16* d = &Xp[dstb][0];
    const float vv[16] = {xr0.x, xr0.y, xr0.z, xr0.w, xr1.x, xr1.y, xr1.z, xr1.w,
                          xr2.x, xr2.y, xr2.z, xr2.w, xr3.x, xr3.y, xr3.z, xr3.w};
    int tt = tt0, i = i00;
    #pragma unroll
    for (int j = 0; j < 16; ++j) {
      d[tt * (NR * XROWF) + sS * XROWF + i] = (_Float16)vv[j];
      ++i;
      if (i == II) { i = 0; ++tt; }
    }
  };

  // ---- zero ALL of Hb (both bufs) and Xp (both bufs): rows TB..15 and pads
  // stay zero forever (stager/gates only touch rows 0..TB-1) ----
  {
    _Float16* hflat = &Hb[0][0];            // 2*NR*HROWF = 4352 f16 (8-divisible)
    for (int i8 = tid; i8 < (2 * NR * HROWF) / 8; i8 += 512)
      *reinterpret_cast<half8*>(hflat + i8 * 8) = (half8){0,0,0,0,0,0,0,0};
    _Float16* xflat = &Xp[0][0];            // 2*XPANEL = 20480 f16
    for (int i8 = tid; i8 < (2 * XPANEL) / 8; i8 += 512)
      *reinterpret_cast<half8*>(xflat + i8 * 8) = (half8){0,0,0,0,0,0,0,0};
  }

  float c[4] = {0.0f, 0.0f, 0.0f, 0.0f};

  xload(0);
  __syncthreads();   // zero-init visible before window-0 writes
  xwrite(0);
  __syncthreads();

  auto step = [&](int tt_idx, const _Float16* Ar, _Float16* Aw, const _Float16* Xr) {
    half8 af[5];
    #pragma unroll
    for (int ks = 0; ks < 4; ++ks)
      af[ks] = *reinterpret_cast<const half8*>(&Ar[col * HROWF + ks * 32 + grp * 8]);
    af[4] = *reinterpret_cast<const half8*>(&Xr[tt_idx * (NR * XROWF) + col * XROWF + grp * 8]);

    f32x4 a0 = {bias[0], bias[0], bias[0], bias[0]};
    f32x4 a1 = {bias[1], bias[1], bias[1], bias[1]};
    f32x4 a2 = {bias[2], bias[2], bias[2], bias[2]};
    f32x4 a3 = {bias[3], bias[3], bias[3], bias[3]};
    #pragma unroll
    for (int ks = 0; ks < 5; ++ks)
      a0 = __builtin_amdgcn_mfma_f32_16x16x32_f16(af[ks], bf[0][ks], a0, 0, 0, 0);
    #pragma unroll
    for (int ks = 0; ks < 5; ++ks)
      a1 = __builtin_amdgcn_mfma_f32_16x16x32_f16(af[ks], bf[1][ks], a1, 0, 0, 0);
    #pragma unroll
    for (int ks = 0; ks < 5; ++ks)
      a2 = __builtin_amdgcn_mfma_f32_16x16x32_f16(af[ks], bf[2][ks], a2, 0, 0, 0);
    #pragma unroll
    for (int ks = 0; ks < 5; ++ks)
      a3 = __builtin_amdgcn_mfma_f32_16x16x32_f16(af[ks], bf[3][ks], a3, 0, 0, 0);

    // fused gates (8 trans/pair), masked to the valid half-wave (rows 0..7)
    if (grp < 2) {
      #pragma unroll
      for (int r = 0; r < 4; ++r) {
        const float Ei = EXP2(-a0[r]);
        const float Ef = EXP2(-a1[r]);
        const float Eg = EXP2(fminf(a2[r], 126.0f));
        const float Eo = EXP2(-a3[r]);
        const float ig = (Eg - 1.0f) * RCP((1.0f + Ei) * (Eg + 1.0f));
        const float ff = RCP(1.0f + Ef);
        const float cn = fmaf(ff, c[r], ig);
        c[r] = cn;
        const float Ec = EXP2(fminf(cn * TWO_L2E, 126.0f));
        const float oth = (Ec - 1.0f) * RCP((1.0f + Eo) * (Ec + 1.0f));
        Aw[(grp * 4 + r) * HROWF + wv * 16 + col] = (_Float16)oth;
      }
    }
    __syncthreads();
  };

  // ================= recurrence: 16 windows x 16 steps =================
  for (int win = 0; win < 16; ++win) {
    const _Float16* Xr = Xp[win & 1];
    if (win + 1 < 16) xload(win + 1);
    for (int k = 0; k < 8; k += 2) {
      step(k,     Hb[0], Hb[1], Xr);
      step(k + 1, Hb[1], Hb[0], Xr);
    }
    if (win + 1 < 16) xwrite((win + 1) & 1);   // other buffer: unread this window
    for (int k = 8; k < 16; k += 2) {
      step(k,     Hb[0], Hb[1], Xr);
      step(k + 1, Hb[1], Hb[0], Xr);
    }
  }

  // ================= head =================
  if (tid < TB * 16) {
    const int s = tid >> 4;          // 0..7
    const int n0 = (tid & 15) * 8;
    float acch[8];
    #pragma unroll
    for (int nj = 0; nj < 8; ++nj) acch[nj] = b0v[n0 + nj];
    #pragma unroll
    for (int kb = 0; kb < 16; ++kb) {
      const half8 hh = *reinterpret_cast<const half8*>(&Hb[0][s * HROWF + kb * 8]);
      float hf[8];
      #pragma unroll
      for (int j = 0; j < 8; ++j) hf[j] = (float)hh[j];
      #pragma unroll
      for (int nj = 0; nj < 8; ++nj) {
        const float4 w0 = *reinterpret_cast<const float4*>(W0 + (n0 + nj) * HH + kb * 8);
        const float4 w1 = *reinterpret_cast<const float4*>(W0 + (n0 + nj) * HH + kb * 8 + 4);
        acch[nj] = fmaf(hf[0], w0.x, fmaf(hf[1], w0.y, fmaf(hf[2], w0.z, fmaf(hf[3], w0.w,
                   fmaf(hf[4], w1.x, fmaf(hf[5], w1.y, fmaf(hf[6], w1.z, fmaf(hf[7], w1.w,
                        acch[nj]))))))));
      }
    }
    #pragma unroll
    for (int nj = 0; nj < 8; ++nj)
      y0ls[s * 132 + n0 + nj] = fmaxf(acch[nj], 0.0f);
  }
  __syncthreads();

  if (tid < TB * 11) {
    const int s = tid / 11;
    const int oo = tid % 11;
    float acc1 = b1v[oo];
    const float4* y4 = reinterpret_cast<const float4*>(y0ls + s * 132);
    const float4* w4 = reinterpret_cast<const float4*>(W1 + oo * HH);
    #pragma unroll 8
    for (int k4 = 0; k4 < 32; ++k4) {
      const float4 yv = y4[k4];
      const float4 wv4 = w4[k4];
      acc1 = fmaf(yv.x, wv4.x, fmaf(yv.y, wv4.y, fmaf(yv.z, wv4.z, fmaf(yv.w, wv4.w, acc1))));
    }
    out[(size_t)(bbase + s) * 11 + oo] = acc1;
  }
}

extern "C" void kernel_launch(void* const* d_in, const int* in_sizes, int n_in,
                              void* d_out, int out_size, void* d_ws, size_t ws_size,
                              hipStream_t stream) {
  const float* x    = (const float*)d_in[0];
  const float* W_ih = (const float*)d_in[1];
  const float* W_hh = (const float*)d_in[2];
  const float* b_ih = (const float*)d_in[3];
  const float* b_hh = (const float*)d_in[4];
  const float* W0   = (const float*)d_in[5];
  const float* b0   = (const float*)d_in[6];
  const float* W1   = (const float*)d_in[7];
  const float* b1   = (const float*)d_in[8];
  float* out = (float*)d_out;
  lstm_mfma<<<512, 512, 0, stream>>>(x, W_ih, W_hh, b_ih, b_hh, W0, b0, W1, b1, out);
}

// Round 11
// 468.255 us; speedup vs baseline: 1.2194x; 1.2194x over previous
//
#include <hip/hip_runtime.h>

#define TT 256
#define II 30
#define HH 128
#define TB 8            // samples per WG -> 512 WGs, 2 WGs/CU
#define NR 16           // MFMA A-tile rows (samples padded with zeros)
#define HROWF 136       // f16 stride for h panel rows (272B)
#define XROWF 40        // f16 stride for x panel rows (80B)
#define XTT 16          // timesteps per staged window
#define XPANEL (XTT * NR * XROWF)   // 10240 f16 per buffer

typedef _Float16 half8 __attribute__((ext_vector_type(8)));
typedef float f32x4 __attribute__((ext_vector_type(4)));

#if __has_builtin(__builtin_amdgcn_exp2f)
#define EXP2(x) __builtin_amdgcn_exp2f(x)
#else
#define EXP2(x) exp2f(x)
#endif
#define RCP(x) __builtin_amdgcn_rcpf(x)

#define L2E 1.44269504089f
#define TWO_L2E 2.88539008177f

// NOTE: launch_bounds (512,2): with (512,4) the allocator quantized to 64 VGPRs
// and spilled bf[] to scratch (round 10: WRITE_SIZE 243MB, dur 571us). (512,2)
// lets it sit at ~104 VGPRs (round 8) which is <=128, so 2 WGs/CU still fit.
__global__ __launch_bounds__(512, 2)
void lstm_mfma(const float* __restrict__ x,
               const float* __restrict__ W_ih,
               const float* __restrict__ W_hh,
               const float* __restrict__ b_ih,
               const float* __restrict__ b_hh,
               const float* __restrict__ W0,
               const float* __restrict__ b0v,
               const float* __restrict__ W1,
               const float* __restrict__ b1v,
               float* __restrict__ out)
{
  __shared__ __align__(16) _Float16 Hb[2][NR * HROWF];
  __shared__ __align__(16) _Float16 Xp[2][XPANEL];
  __shared__ float y0ls[TB * 132];

  const int tid = threadIdx.x;
  const int bbase = blockIdx.x * TB;
  const int wv = tid >> 6;      // wave 0..7
  const int lane = tid & 63;
  const int col = lane & 15;    // A-row (sample) / D-col (unit)
  const int grp = lane >> 4;    // k-slot group / D-row block

  // ---- B-fragments (pre-scaled for exp2 gates); wave wv owns units wv*16+col,
  // lane holds i,f,g,o preacts of the SAME unit -> gate math lane-local ----
  half8 bf[4][5];
  float bias[4];
  #pragma unroll
  for (int g = 0; g < 4; ++g) {
    const float sc = (g == 2) ? TWO_L2E : L2E;
    const int n = g * 128 + wv * 16 + col;
    #pragma unroll
    for (int ks = 0; ks < 4; ++ks) {
      const float4 p = *reinterpret_cast<const float4*>(W_hh + n * HH + ks * 32 + grp * 8);
      const float4 q = *reinterpret_cast<const float4*>(W_hh + n * HH + ks * 32 + grp * 8 + 4);
      bf[g][ks] = (half8){(_Float16)(p.x * sc), (_Float16)(p.y * sc),
                          (_Float16)(p.z * sc), (_Float16)(p.w * sc),
                          (_Float16)(q.x * sc), (_Float16)(q.y * sc),
                          (_Float16)(q.z * sc), (_Float16)(q.w * sc)};
    }
    {
      float v[8];
      #pragma unroll
      for (int j = 0; j < 8; ++j) {
        const int cc = grp * 8 + j;
        v[j] = (cc < II) ? W_ih[n * II + cc] * sc : 0.0f;
      }
      bf[g][4] = (half8){(_Float16)v[0], (_Float16)v[1], (_Float16)v[2], (_Float16)v[3],
                         (_Float16)v[4], (_Float16)v[5], (_Float16)v[6], (_Float16)v[7]};
    }
    bias[g] = (b_ih[n] + b_hh[n]) * sc;
  }

  // ---- x stager: 240 threads x 16 consecutive floats per window ----
  const bool stg = (tid < 240);
  const int sS = stg ? (tid / 30) : 7;   // 0..7
  const int qS = tid % 30;
  const int g0 = qS * 16;
  const int tt0 = g0 / 30;
  const int i00 = g0 % 30;
  const float* wbase = x + (size_t)(bbase + sS) * (TT * II);

  float4 xr0, xr1, xr2, xr3;
  auto xload = [&](int win) {
    if (!stg) return;
    const float* p = wbase + win * (XTT * II) + g0;   // 64B-aligned
    xr0 = *reinterpret_cast<const float4*>(p);
    xr1 = *reinterpret_cast<const float4*>(p + 4);
    xr2 = *reinterpret_cast<const float4*>(p + 8);
    xr3 = *reinterpret_cast<const float4*>(p + 12);
  };
  auto xwrite = [&](int dstb) {
    if (!stg) return;
    _Float16* d = &Xp[dstb][0];
    const float vv[16] = {xr0.x, xr0.y, xr0.z, xr0.w, xr1.x, xr1.y, xr1.z, xr1.w,
                          xr2.x, xr2.y, xr2.z, xr2.w, xr3.x, xr3.y, xr3.z, xr3.w};
    int tt = tt0, i = i00;
    #pragma unroll
    for (int j = 0; j < 16; ++j) {
      d[tt * (NR * XROWF) + sS * XROWF + i] = (_Float16)vv[j];
      ++i;
      if (i == II) { i = 0; ++tt; }
    }
  };

  // ---- zero ALL of Hb (both bufs) and Xp (both bufs): rows TB..15 and pads
  // stay zero forever (stager/gates only touch rows 0..TB-1) ----
  {
    _Float16* hflat = &Hb[0][0];            // 2*NR*HROWF = 4352 f16
    for (int i8 = tid; i8 < (2 * NR * HROWF) / 8; i8 += 512)
      *reinterpret_cast<half8*>(hflat + i8 * 8) = (half8){0,0,0,0,0,0,0,0};
    _Float16* xflat = &Xp[0][0];            // 2*XPANEL = 20480 f16
    for (int i8 = tid; i8 < (2 * XPANEL) / 8; i8 += 512)
      *reinterpret_cast<half8*>(xflat + i8 * 8) = (half8){0,0,0,0,0,0,0,0};
  }

  float c[4] = {0.0f, 0.0f, 0.0f, 0.0f};

  xload(0);
  __syncthreads();   // zero-init visible before window-0 writes
  xwrite(0);
  __syncthreads();

  auto step = [&](int tt_idx, const _Float16* Ar, _Float16* Aw, const _Float16* Xr) {
    half8 af[5];
    #pragma unroll
    for (int ks = 0; ks < 4; ++ks)
      af[ks] = *reinterpret_cast<const half8*>(&Ar[col * HROWF + ks * 32 + grp * 8]);
    af[4] = *reinterpret_cast<const half8*>(&Xr[tt_idx * (NR * XROWF) + col * XROWF + grp * 8]);

    f32x4 a0 = {bias[0], bias[0], bias[0], bias[0]};
    f32x4 a1 = {bias[1], bias[1], bias[1], bias[1]};
    f32x4 a2 = {bias[2], bias[2], bias[2], bias[2]};
    f32x4 a3 = {bias[3], bias[3], bias[3], bias[3]};
    #pragma unroll
    for (int ks = 0; ks < 5; ++ks)
      a0 = __builtin_amdgcn_mfma_f32_16x16x32_f16(af[ks], bf[0][ks], a0, 0, 0, 0);
    #pragma unroll
    for (int ks = 0; ks < 5; ++ks)
      a1 = __builtin_amdgcn_mfma_f32_16x16x32_f16(af[ks], bf[1][ks], a1, 0, 0, 0);
    #pragma unroll
    for (int ks = 0; ks < 5; ++ks)
      a2 = __builtin_amdgcn_mfma_f32_16x16x32_f16(af[ks], bf[2][ks], a2, 0, 0, 0);
    #pragma unroll
    for (int ks = 0; ks < 5; ++ks)
      a3 = __builtin_amdgcn_mfma_f32_16x16x32_f16(af[ks], bf[3][ks], a3, 0, 0, 0);

    // fused gates (8 trans/pair), masked to the valid half-wave (rows 0..7)
    if (grp < 2) {
      #pragma unroll
      for (int r = 0; r < 4; ++r) {
        const float Ei = EXP2(-a0[r]);
        const float Ef = EXP2(-a1[r]);
        const float Eg = EXP2(fminf(a2[r], 126.0f));
        const float Eo = EXP2(-a3[r]);
        const float ig = (Eg - 1.0f) * RCP((1.0f + Ei) * (Eg + 1.0f));
        const float ff = RCP(1.0f + Ef);
        const float cn = fmaf(ff, c[r], ig);
        c[r] = cn;
        const float Ec = EXP2(fminf(cn * TWO_L2E, 126.0f));
        const float oth = (Ec - 1.0f) * RCP((1.0f + Eo) * (Ec + 1.0f));
        Aw[(grp * 4 + r) * HROWF + wv * 16 + col] = (_Float16)oth;
      }
    }
    __syncthreads();
  };

  // ================= recurrence: 16 windows x 16 steps =================
  for (int win = 0; win < 16; ++win) {
    const _Float16* Xr = Xp[win & 1];
    if (win + 1 < 16) xload(win + 1);
    for (int k = 0; k < 8; k += 2) {
      step(k,     Hb[0], Hb[1], Xr);
      step(k + 1, Hb[1], Hb[0], Xr);
    }
    if (win + 1 < 16) xwrite((win + 1) & 1);   // other buffer: unread this window
    for (int k = 8; k < 16; k += 2) {
      step(k,     Hb[0], Hb[1], Xr);
      step(k + 1, Hb[1], Hb[0], Xr);
    }
  }

  // ================= head =================
  if (tid < TB * 16) {
    const int s = tid >> 4;          // 0..7
    const int n0 = (tid & 15) * 8;
    float acch[8];
    #pragma unroll
    for (int nj = 0; nj < 8; ++nj) acch[nj] = b0v[n0 + nj];
    #pragma unroll
    for (int kb = 0; kb < 16; ++kb) {
      const half8 hh = *reinterpret_cast<const half8*>(&Hb[0][s * HROWF + kb * 8]);
      float hf[8];
      #pragma unroll
      for (int j = 0; j < 8; ++j) hf[j] = (float)hh[j];
      #pragma unroll
      for (int nj = 0; nj < 8; ++nj) {
        const float4 w0 = *reinterpret_cast<const float4*>(W0 + (n0 + nj) * HH + kb * 8);
        const float4 w1 = *reinterpret_cast<const float4*>(W0 + (n0 + nj) * HH + kb * 8 + 4);
        acch[nj] = fmaf(hf[0], w0.x, fmaf(hf[1], w0.y, fmaf(hf[2], w0.z, fmaf(hf[3], w0.w,
                   fmaf(hf[4], w1.x, fmaf(hf[5], w1.y, fmaf(hf[6], w1.z, fmaf(hf[7], w1.w,
                        acch[nj]))))))));
      }
    }
    #pragma unroll
    for (int nj = 0; nj < 8; ++nj)
      y0ls[s * 132 + n0 + nj] = fmaxf(acch[nj], 0.0f);
  }
  __syncthreads();

  if (tid < TB * 11) {
    const int s = tid / 11;
    const int oo = tid % 11;
    float acc1 = b1v[oo];
    const float4* y4 = reinterpret_cast<const float4*>(y0ls + s * 132);
    const float4* w4 = reinterpret_cast<const float4*>(W1 + oo * HH);
    #pragma unroll 8
    for (int k4 = 0; k4 < 32; ++k4) {
      const float4 yv = y4[k4];
      const float4 wv4 = w4[k4];
      acc1 = fmaf(yv.x, wv4.x, fmaf(yv.y, wv4.y, fmaf(yv.z, wv4.z, fmaf(yv.w, wv4.w, acc1))));
    }
    out[(size_t)(bbase + s) * 11 + oo] = acc1;
  }
}

extern "C" void kernel_launch(void* const* d_in, const int* in_sizes, int n_in,
                              void* d_out, int out_size, void* d_ws, size_t ws_size,
                              hipStream_t stream) {
  const float* x    = (const float*)d_in[0];
  const float* W_ih = (const float*)d_in[1];
  const float* W_hh = (const float*)d_in[2];
  const float* b_ih = (const float*)d_in[3];
  const float* b_hh = (const float*)d_in[4];
  const float* W0   = (const float*)d_in[5];
  const float* b0   = (const float*)d_in[6];
  const float* W1   = (const float*)d_in[7];
  const float* b1   = (const float*)d_in[8];
  float* out = (float*)d_out;
  lstm_mfma<<<512, 512, 0, stream>>>(x, W_ih, W_hh, b_ih, b_hh, W0, b0, W1, b1, out);
}

// Round 13
// 371.068 us; speedup vs baseline: 1.5388x; 1.2619x over previous
//
#include <hip/hip_runtime.h>

#define TT 256
#define II 30
#define HH 128
#define TB 8            // samples per WG -> 512 WGs
#define HROWF 136       // f16 stride for h panel rows (272B)
#define XROWF 40        // f16 stride for x panel rows (80B)
#define XTT 16          // timesteps per staged window
#define XPANEL (XTT * TB * XROWF)   // 5120 f16 per buffer

typedef _Float16 half8 __attribute__((ext_vector_type(8)));
typedef float f32x4 __attribute__((ext_vector_type(4)));

#define EXP2(x) __builtin_amdgcn_exp2f(x)
#define RCP(x) __builtin_amdgcn_rcpf(x)
#define L2E 1.44269504089f
#define TWO_L2E 2.88539008177f

__global__ __launch_bounds__(512, 2)
void lstm_mfma(const float* __restrict__ x,
               const float* __restrict__ W_ih,
               const float* __restrict__ W_hh,
               const float* __restrict__ b_ih,
               const float* __restrict__ b_hh,
               const float* __restrict__ W0,
               const float* __restrict__ b0v,
               const float* __restrict__ W1,
               const float* __restrict__ b1v,
               float* __restrict__ out)
{
  __shared__ __align__(16) _Float16 Hb[2][TB * HROWF];   // 8 rows per buffer
  __shared__ __align__(16) _Float16 Xp[2][XPANEL];       // 8 rows per (buf,tt)
  __shared__ float y0ls[TB * 132];

  const int tid = threadIdx.x;
  const int bbase = blockIdx.x * TB;
  const int wv = tid >> 6;      // wave 0..7
  const int lane = tid & 63;
  const int col = lane & 15;    // A-tile row index source / D-col (unit)
  const int grp = lane >> 4;    // k-slot group / D-row block
  const int row8 = col & 7;     // duplicated A-row: rows 8-15 mirror 0-7

  // ---- B-fragments (pre-scaled for exp2 gates); wave wv owns units wv*16+col ----
  half8 bf[4][5];
  float bias[4];
  #pragma unroll
  for (int g = 0; g < 4; ++g) {
    const float sc0 = (g == 2) ? TWO_L2E : L2E;
    const int n = g * 128 + wv * 16 + col;
    #pragma unroll
    for (int ks = 0; ks < 4; ++ks) {
      const float4 p = *reinterpret_cast<const float4*>(W_hh + n * HH + ks * 32 + grp * 8);
      const float4 q = *reinterpret_cast<const float4*>(W_hh + n * HH + ks * 32 + grp * 8 + 4);
      bf[g][ks] = (half8){(_Float16)(p.x * sc0), (_Float16)(p.y * sc0),
                          (_Float16)(p.z * sc0), (_Float16)(p.w * sc0),
                          (_Float16)(q.x * sc0), (_Float16)(q.y * sc0),
                          (_Float16)(q.z * sc0), (_Float16)(q.w * sc0)};
    }
    {
      float v[8];
      #pragma unroll
      for (int j = 0; j < 8; ++j) {
        const int cc = grp * 8 + j;
        v[j] = (cc < II) ? W_ih[n * II + cc] * sc0 : 0.0f;
      }
      bf[g][4] = (half8){(_Float16)v[0], (_Float16)v[1], (_Float16)v[2], (_Float16)v[3],
                         (_Float16)v[4], (_Float16)v[5], (_Float16)v[6], (_Float16)v[7]};
    }
    bias[g] = (b_ih[n] + b_hh[n]) * sc0;
  }

  // ---- x stager: 240 threads x 16 consecutive floats per window (rows 0..7) ----
  const bool stg = (tid < 240);
  const int sS = stg ? (tid / 30) : 7;
  const int qS = tid % 30;
  const int g0 = qS * 16;
  const int tt0 = g0 / II;
  const int i00 = g0 % II;
  const float* wbase = x + (size_t)(bbase + sS) * (TT * II);

  float4 xr0, xr1, xr2, xr3;
  auto xload = [&](int win) {
    if (!stg) return;
    const float* p = wbase + win * (XTT * II) + g0;   // 64B-aligned
    xr0 = *reinterpret_cast<const float4*>(p);
    xr1 = *reinterpret_cast<const float4*>(p + 4);
    xr2 = *reinterpret_cast<const float4*>(p + 8);
    xr3 = *reinterpret_cast<const float4*>(p + 12);
  };
  auto xwrite = [&](int dstb) {
    if (!stg) return;
    _Float16* d = &Xp[dstb][0];
    const float vv[16] = {xr0.x, xr0.y, xr0.z, xr0.w, xr1.x, xr1.y, xr1.z, xr1.w,
                          xr2.x, xr2.y, xr2.z, xr2.w, xr3.x, xr3.y, xr3.z, xr3.w};
    int tt = tt0, i = i00;
    #pragma unroll
    for (int j = 0; j < 16; ++j) {
      d[tt * (TB * XROWF) + sS * XROWF + i] = (_Float16)vv[j];
      ++i;
      if (i == II) { i = 0; ++tt; }
    }
  };

  // ---- zero ALL of Hb and Xp (pads included; h(0)=0) ----
  {
    _Float16* hflat = &Hb[0][0];            // 2*8*136 = 2176 f16
    for (int i8 = tid; i8 < (2 * TB * HROWF) / 8; i8 += 512)
      *reinterpret_cast<half8*>(hflat + i8 * 8) = (half8){0,0,0,0,0,0,0,0};
    _Float16* xflat = &Xp[0][0];            // 2*5120 = 10240 f16
    for (int i8 = tid; i8 < (2 * XPANEL) / 8; i8 += 512)
      *reinterpret_cast<half8*>(xflat + i8 * 8) = (half8){0,0,0,0,0,0,0,0};
  }

  float c[2] = {0.0f, 0.0f};
  const int rb = grp & 2;   // grp0,1 -> gates r=0,1 ; grp2,3 -> gates r=2,3 (dup rows)

  xload(0);
  __syncthreads();   // zero-init visible before window-0 writes
  xwrite(0);
  __syncthreads();

  auto step = [&](int tt_idx, const _Float16* Ar, _Float16* Aw, const _Float16* Xr) {
    half8 af[5];
    #pragma unroll
    for (int ks = 0; ks < 4; ++ks)
      af[ks] = *reinterpret_cast<const half8*>(&Ar[row8 * HROWF + ks * 32 + grp * 8]);
    af[4] = *reinterpret_cast<const half8*>(&Xr[tt_idx * (TB * XROWF) + row8 * XROWF + grp * 8]);

    f32x4 a0 = {bias[0], bias[0], bias[0], bias[0]};
    f32x4 a1 = {bias[1], bias[1], bias[1], bias[1]};
    f32x4 a2 = {bias[2], bias[2], bias[2], bias[2]};
    f32x4 a3 = {bias[3], bias[3], bias[3], bias[3]};
    #pragma unroll
    for (int ks = 0; ks < 5; ++ks)
      a0 = __builtin_amdgcn_mfma_f32_16x16x32_f16(af[ks], bf[0][ks], a0, 0, 0, 0);
    #pragma unroll
    for (int ks = 0; ks < 5; ++ks)
      a1 = __builtin_amdgcn_mfma_f32_16x16x32_f16(af[ks], bf[1][ks], a1, 0, 0, 0);
    #pragma unroll
    for (int ks = 0; ks < 5; ++ks)
      a2 = __builtin_amdgcn_mfma_f32_16x16x32_f16(af[ks], bf[2][ks], a2, 0, 0, 0);
    #pragma unroll
    for (int ks = 0; ks < 5; ++ks)
      a3 = __builtin_amdgcn_mfma_f32_16x16x32_f16(af[ks], bf[3][ks], a3, 0, 0, 0);

    // gates: ALL lanes active, 2 (sample,unit) pairs each.
    // D rows 8-15 duplicate rows 0-7, so grp2/3 regs r=2,3 hold samples 2,3 / 6,7.
    #pragma unroll
    for (int rr = 0; rr < 2; ++rr) {
      const int r = rb + rr;
      const float p0 = a0[r], p1 = a1[r], p2 = a2[r], p3 = a3[r];
      const float Ei = EXP2(-p0);
      const float Ef = EXP2(-p1);
      const float Eg = EXP2(fminf(p2, 126.0f));
      const float Eo = EXP2(-p3);
      const float ig = (Eg - 1.0f) * RCP((1.0f + Ei) * (Eg + 1.0f));
      const float ff = RCP(1.0f + Ef);
      const float cn = fmaf(ff, c[rr], ig);
      c[rr] = cn;
      const float Ec = EXP2(fminf(cn * TWO_L2E, 126.0f));
      const float oth = (Ec - 1.0f) * RCP((1.0f + Eo) * (Ec + 1.0f));
      Aw[((grp * 4 + r) & 7) * HROWF + wv * 16 + col] = (_Float16)oth;
    }
    __syncthreads();
  };

  // ================= recurrence: 16 windows x 16 steps =================
  for (int win = 0; win < 16; ++win) {
    const _Float16* Xr = Xp[win & 1];
    if (win + 1 < 16) xload(win + 1);
    for (int k = 0; k < 8; k += 2) {
      step(k,     Hb[0], Hb[1], Xr);
      step(k + 1, Hb[1], Hb[0], Xr);
    }
    if (win + 1 < 16) xwrite((win + 1) & 1);   // other buffer: unread this window
    for (int k = 8; k < 16; k += 2) {
      step(k,     Hb[0], Hb[1], Xr);
      step(k + 1, Hb[1], Hb[0], Xr);
    }
  }

  // ================= head =================
  if (tid < TB * 16) {
    const int s = tid >> 4;          // 0..7
    const int n0 = (tid & 15) * 8;
    float acch[8];
    #pragma unroll
    for (int nj = 0; nj < 8; ++nj) acch[nj] = b0v[n0 + nj];
    #pragma unroll
    for (int kb = 0; kb < 16; ++kb) {
      const half8 hh = *reinterpret_cast<const half8*>(&Hb[0][s * HROWF + kb * 8]);
      float hf[8];
      #pragma unroll
      for (int j = 0; j < 8; ++j) hf[j] = (float)hh[j];
      #pragma unroll
      for (int nj = 0; nj < 8; ++nj) {
        const float4 w0 = *reinterpret_cast<const float4*>(W0 + (n0 + nj) * HH + kb * 8);
        const float4 w1 = *reinterpret_cast<const float4*>(W0 + (n0 + nj) * HH + kb * 8 + 4);
        acch[nj] = fmaf(hf[0], w0.x, fmaf(hf[1], w0.y, fmaf(hf[2], w0.z, fmaf(hf[3], w0.w,
                   fmaf(hf[4], w1.x, fmaf(hf[5], w1.y, fmaf(hf[6], w1.z, fmaf(hf[7], w1.w,
                        acch[nj]))))))));
      }
    }
    #pragma unroll
    for (int nj = 0; nj < 8; ++nj)
      y0ls[s * 132 + n0 + nj] = fmaxf(acch[nj], 0.0f);
  }
  __syncthreads();

  if (tid < TB * 11) {
    const int s = tid / 11;
    const int oo = tid % 11;
    float acc1 = b1v[oo];
    const float4* y4 = reinterpret_cast<const float4*>(y0ls + s * 132);
    const float4* w4 = reinterpret_cast<const float4*>(W1 + oo * HH);
    #pragma unroll 8
    for (int k4 = 0; k4 < 32; ++k4) {
      const float4 yv = y4[k4];
      const float4 wv4 = w4[k4];
      acc1 = fmaf(yv.x, wv4.x, fmaf(yv.y, wv4.y, fmaf(yv.z, wv4.z, fmaf(yv.w, wv4.w, acc1))));
    }
    out[(size_t)(bbase + s) * 11 + oo] = acc1;
  }
}

extern "C" void kernel_launch(void* const* d_in, const int* in_sizes, int n_in,
                              void* d_out, int out_size, void* d_ws, size_t ws_size,
                              hipStream_t stream) {
  const float* x    = (const float*)d_in[0];
  const float* W_ih = (const float*)d_in[1];
  const float* W_hh = (const float*)d_in[2];
  const float* b_ih = (const float*)d_in[3];
  const float* b_hh = (const float*)d_in[4];
  const float* W0   = (const float*)d_in[5];
  const float* b0   = (const float*)d_in[6];
  const float* W1   = (const float*)d_in[7];
  const float* b1   = (const float*)d_in[8];
  float* out = (float*)d_out;
  lstm_mfma<<<512, 512, 0, stream>>>(x, W_ih, W_hh, b_ih, b_hh, W0, b0, W1, b1, out);
}

// Round 14
// 359.676 us; speedup vs baseline: 1.5875x; 1.0317x over previous
//
#include <hip/hip_runtime.h>

#define TT 256
#define II 30
#define HH 128
#define TBG 8           // samples per group; 2 groups per WG -> 16 samples, 256 WGs
#define HROWF 136       // f16 stride for h panel rows (272B)
#define XROWF 40        // f16 stride for x panel rows (80B)
#define XTT 16          // timesteps per staged window
#define XPANEL (XTT * TBG * XROWF)   // 5120 f16 per buffer

typedef _Float16 half8 __attribute__((ext_vector_type(8)));
typedef float f32x4 __attribute__((ext_vector_type(4)));

#define EXP2(x) __builtin_amdgcn_exp2f(x)
#define RCP(x) __builtin_amdgcn_rcpf(x)
#define L2E 1.44269504089f
#define TWO_L2E 2.88539008177f

__global__ __launch_bounds__(512, 2)
void lstm_mfma(const float* __restrict__ x,
               const float* __restrict__ W_ih,
               const float* __restrict__ W_hh,
               const float* __restrict__ b_ih,
               const float* __restrict__ b_hh,
               const float* __restrict__ W0,
               const float* __restrict__ b0v,
               const float* __restrict__ W1,
               const float* __restrict__ b1v,
               float* __restrict__ out)
{
  __shared__ __align__(16) _Float16 HbA[2][TBG * HROWF];
  __shared__ __align__(16) _Float16 HbB[2][TBG * HROWF];
  __shared__ __align__(16) _Float16 XpA[2][XPANEL];
  __shared__ __align__(16) _Float16 XpB[2][XPANEL];
  __shared__ float y0ls[16 * 132];

  const int tid = threadIdx.x;
  const int bbase = blockIdx.x * 16;
  const int wv = tid >> 6;      // wave 0..7
  const int lane = tid & 63;
  const int col = lane & 15;
  const int grp = lane >> 4;
  const int row8 = col & 7;     // duplicated A-row: rows 8-15 mirror 0-7 (r13-proven)

  // ---- B-fragments (pre-scaled for exp2 gates); r13 verbatim ----
  half8 bf[4][5];
  float bias[4];
  #pragma unroll
  for (int g = 0; g < 4; ++g) {
    const float sc0 = (g == 2) ? TWO_L2E : L2E;
    const int n = g * 128 + wv * 16 + col;
    #pragma unroll
    for (int ks = 0; ks < 4; ++ks) {
      const float4 p = *reinterpret_cast<const float4*>(W_hh + n * HH + ks * 32 + grp * 8);
      const float4 q = *reinterpret_cast<const float4*>(W_hh + n * HH + ks * 32 + grp * 8 + 4);
      bf[g][ks] = (half8){(_Float16)(p.x * sc0), (_Float16)(p.y * sc0),
                          (_Float16)(p.z * sc0), (_Float16)(p.w * sc0),
                          (_Float16)(q.x * sc0), (_Float16)(q.y * sc0),
                          (_Float16)(q.z * sc0), (_Float16)(q.w * sc0)};
    }
    {
      float v[8];
      #pragma unroll
      for (int j = 0; j < 8; ++j) {
        const int cc = grp * 8 + j;
        v[j] = (cc < II) ? W_ih[n * II + cc] * sc0 : 0.0f;
      }
      bf[g][4] = (half8){(_Float16)v[0], (_Float16)v[1], (_Float16)v[2], (_Float16)v[3],
                         (_Float16)v[4], (_Float16)v[5], (_Float16)v[6], (_Float16)v[7]};
    }
    bias[g] = (b_ih[n] + b_hh[n]) * sc0;
  }

  // ---- stagers (r13's 240-thread pattern, twice on disjoint lanes) ----
  // kind 0: tid 0..239 -> group A (samples bbase+0..7)
  // kind 1: tid 256..495 -> group B (samples bbase+8..15)
  const int stgKind = (tid < 240) ? 0 : ((tid >= 256 && tid < 496) ? 1 : 2);
  const int lidx = (stgKind == 1) ? (tid - 256) : tid;   // 0..239 for stagers
  const int sS = (stgKind == 2) ? 7 : (lidx / 30);       // group-local sample 0..7
  const int qS = lidx % 30;
  const int g0 = qS * 16;
  const int tt0 = g0 / II;
  const int i00 = g0 % II;
  const int sGlob = sS + (stgKind == 1 ? TBG : 0);
  const float* wbase = x + (size_t)(bbase + sGlob) * (TT * II);

  float4 xr0, xr1, xr2, xr3;
  auto xload = [&](int win) {
    if (stgKind == 2) return;
    const float* p = wbase + win * (XTT * II) + g0;   // 64B-aligned
    xr0 = *reinterpret_cast<const float4*>(p);
    xr1 = *reinterpret_cast<const float4*>(p + 4);
    xr2 = *reinterpret_cast<const float4*>(p + 8);
    xr3 = *reinterpret_cast<const float4*>(p + 12);
  };
  auto xwrite = [&](int dstb) {
    if (stgKind == 2) return;
    _Float16* d = (stgKind == 0) ? &XpA[dstb][0] : &XpB[dstb][0];
    const float vv[16] = {xr0.x, xr0.y, xr0.z, xr0.w, xr1.x, xr1.y, xr1.z, xr1.w,
                          xr2.x, xr2.y, xr2.z, xr2.w, xr3.x, xr3.y, xr3.z, xr3.w};
    int tt = tt0, i = i00;
    #pragma unroll
    for (int j = 0; j < 16; ++j) {
      d[tt * (TBG * XROWF) + sS * XROWF + i] = (_Float16)vv[j];
      ++i;
      if (i == II) { i = 0; ++tt; }
    }
  };

  // ---- zero ALL h and x panels (pads included; h(0)=0) ----
  {
    _Float16* hA = &HbA[0][0];
    for (int i8 = tid; i8 < (2 * TBG * HROWF) / 8; i8 += 512)
      *reinterpret_cast<half8*>(hA + i8 * 8) = (half8){0,0,0,0,0,0,0,0};
    _Float16* hB = &HbB[0][0];
    for (int i8 = tid; i8 < (2 * TBG * HROWF) / 8; i8 += 512)
      *reinterpret_cast<half8*>(hB + i8 * 8) = (half8){0,0,0,0,0,0,0,0};
    _Float16* xA = &XpA[0][0];
    for (int i8 = tid; i8 < (2 * XPANEL) / 8; i8 += 512)
      *reinterpret_cast<half8*>(xA + i8 * 8) = (half8){0,0,0,0,0,0,0,0};
    _Float16* xB = &XpB[0][0];
    for (int i8 = tid; i8 < (2 * XPANEL) / 8; i8 += 512)
      *reinterpret_cast<half8*>(xB + i8 * 8) = (half8){0,0,0,0,0,0,0,0};
  }

  float cA[2] = {0.0f, 0.0f};
  float cB[2] = {0.0f, 0.0f};
  const int rb = grp & 2;   // r13-proven gate split

  xload(0);
  __syncthreads();   // zero-init visible before window-0 writes
  xwrite(0);
  __syncthreads();

  // ---- one group-step: r13's proven body, barrier hoisted to caller ----
  auto step = [&](int tt_idx, const _Float16* Ar, _Float16* Aw, const _Float16* Xr,
                  float (&c)[2]) {
    half8 af[5];
    #pragma unroll
    for (int ks = 0; ks < 4; ++ks)
      af[ks] = *reinterpret_cast<const half8*>(&Ar[row8 * HROWF + ks * 32 + grp * 8]);
    af[4] = *reinterpret_cast<const half8*>(&Xr[tt_idx * (TBG * XROWF) + row8 * XROWF + grp * 8]);

    f32x4 a0 = {bias[0], bias[0], bias[0], bias[0]};
    f32x4 a1 = {bias[1], bias[1], bias[1], bias[1]};
    f32x4 a2 = {bias[2], bias[2], bias[2], bias[2]};
    f32x4 a3 = {bias[3], bias[3], bias[3], bias[3]};
    #pragma unroll
    for (int ks = 0; ks < 5; ++ks)
      a0 = __builtin_amdgcn_mfma_f32_16x16x32_f16(af[ks], bf[0][ks], a0, 0, 0, 0);
    #pragma unroll
    for (int ks = 0; ks < 5; ++ks)
      a1 = __builtin_amdgcn_mfma_f32_16x16x32_f16(af[ks], bf[1][ks], a1, 0, 0, 0);
    #pragma unroll
    for (int ks = 0; ks < 5; ++ks)
      a2 = __builtin_amdgcn_mfma_f32_16x16x32_f16(af[ks], bf[2][ks], a2, 0, 0, 0);
    #pragma unroll
    for (int ks = 0; ks < 5; ++ks)
      a3 = __builtin_amdgcn_mfma_f32_16x16x32_f16(af[ks], bf[3][ks], a3, 0, 0, 0);

    #pragma unroll
    for (int rr = 0; rr < 2; ++rr) {
      const int r = rb + rr;
      const float p0 = a0[r], p1 = a1[r], p2 = a2[r], p3 = a3[r];
      const float Ei = EXP2(-p0);
      const float Ef = EXP2(-p1);
      const float Eg = EXP2(fminf(p2, 126.0f));
      const float Eo = EXP2(-p3);
      const float ig = (Eg - 1.0f) * RCP((1.0f + Ei) * (Eg + 1.0f));
      const float ff = RCP(1.0f + Ef);
      const float cn = fmaf(ff, c[rr], ig);
      c[rr] = cn;
      const float Ec = EXP2(fminf(cn * TWO_L2E, 126.0f));
      const float oth = (Ec - 1.0f) * RCP((1.0f + Eo) * (Ec + 1.0f));
      Aw[((grp * 4 + r) & 7) * HROWF + wv * 16 + col] = (_Float16)oth;
    }
  };

  // ================= recurrence: 16 windows x 16 pair-steps =================
  for (int win = 0; win < 16; ++win) {
    const _Float16* XrA = &XpA[win & 1][0];
    const _Float16* XrB = &XpB[win & 1][0];
    if (win + 1 < 16) xload(win + 1);
    for (int k = 0; k < 8; k += 2) {
      step(k,     &HbA[0][0], &HbA[1][0], XrA, cA);
      step(k,     &HbB[0][0], &HbB[1][0], XrB, cB);
      __syncthreads();
      step(k + 1, &HbA[1][0], &HbA[0][0], XrA, cA);
      step(k + 1, &HbB[1][0], &HbB[0][0], XrB, cB);
      __syncthreads();
    }
    if (win + 1 < 16) xwrite((win + 1) & 1);   // other buffer: unread this window
    for (int k = 8; k < 16; k += 2) {
      step(k,     &HbA[0][0], &HbA[1][0], XrA, cA);
      step(k,     &HbB[0][0], &HbB[1][0], XrB, cB);
      __syncthreads();
      step(k + 1, &HbA[1][0], &HbA[0][0], XrA, cA);
      step(k + 1, &HbB[1][0], &HbB[0][0], XrB, cB);
      __syncthreads();
    }
  }

  // ================= head =================
  if (tid < 256) {
    const int s = tid >> 4;          // 0..15
    const int n0 = (tid & 15) * 8;
    const _Float16* hrow = (s < TBG) ? &HbA[0][(s & 7) * HROWF]
                                     : &HbB[0][(s & 7) * HROWF];
    float acch[8];
    #pragma unroll
    for (int nj = 0; nj < 8; ++nj) acch[nj] = b0v[n0 + nj];
    #pragma unroll
    for (int kb = 0; kb < 16; ++kb) {
      const half8 hh = *reinterpret_cast<const half8*>(&hrow[kb * 8]);
      float hf[8];
      #pragma unroll
      for (int j = 0; j < 8; ++j) hf[j] = (float)hh[j];
      #pragma unroll
      for (int nj = 0; nj < 8; ++nj) {
        const float4 w0 = *reinterpret_cast<const float4*>(W0 + (n0 + nj) * HH + kb * 8);
        const float4 w1 = *reinterpret_cast<const float4*>(W0 + (n0 + nj) * HH + kb * 8 + 4);
        acch[nj] = fmaf(hf[0], w0.x, fmaf(hf[1], w0.y, fmaf(hf[2], w0.z, fmaf(hf[3], w0.w,
                   fmaf(hf[4], w1.x, fmaf(hf[5], w1.y, fmaf(hf[6], w1.z, fmaf(hf[7], w1.w,
                        acch[nj]))))))));
      }
    }
    #pragma unroll
    for (int nj = 0; nj < 8; ++nj)
      y0ls[s * 132 + n0 + nj] = fmaxf(acch[nj], 0.0f);
  }
  __syncthreads();

  if (tid < 16 * 11) {
    const int s = tid / 11;
    const int oo = tid % 11;
    float acc1 = b1v[oo];
    const float4* y4 = reinterpret_cast<const float4*>(y0ls + s * 132);
    const float4* w4 = reinterpret_cast<const float4*>(W1 + oo * HH);
    #pragma unroll 8
    for (int k4 = 0; k4 < 32; ++k4) {
      const float4 yv = y4[k4];
      const float4 wv4 = w4[k4];
      acc1 = fmaf(yv.x, wv4.x, fmaf(yv.y, wv4.y, fmaf(yv.z, wv4.z, fmaf(yv.w, wv4.w, acc1))));
    }
    out[(size_t)(bbase + s) * 11 + oo] = acc1;
  }
}

extern "C" void kernel_launch(void* const* d_in, const int* in_sizes, int n_in,
                              void* d_out, int out_size, void* d_ws, size_t ws_size,
                              hipStream_t stream) {
  const float* x    = (const float*)d_in[0];
  const float* W_ih = (const float*)d_in[1];
  const float* W_hh = (const float*)d_in[2];
  const float* b_ih = (const float*)d_in[3];
  const float* b_hh = (const float*)d_in[4];
  const float* W0   = (const float*)d_in[5];
  const float* b0   = (const float*)d_in[6];
  const float* W1   = (const float*)d_in[7];
  const float* b1   = (const float*)d_in[8];
  float* out = (float*)d_out;
  lstm_mfma<<<256, 512, 0, stream>>>(x, W_ih, W_hh, b_ih, b_hh, W0, b0, W1, b1, out);
}

// Round 16
// 246.742 us; speedup vs baseline: 2.3141x; 1.4577x over previous
//
#include <hip/hip_runtime.h>

#define TT 256
#define II 30
#define HH 128
#define TB 16           // samples per WG -> 256 WGs, one batch
#define HROWF 136       // f16 stride for h panel rows (272B)
#define XROWF 40        // f16 stride for x panel rows (80B)
#define XTT 16          // timesteps per staged window
#define XPANEL (XTT * TB * XROWF)   // 10240 f16 per buffer

typedef _Float16 half8 __attribute__((ext_vector_type(8)));
typedef float f32x4 __attribute__((ext_vector_type(4)));

#define EXP2(x) __builtin_amdgcn_exp2f(x)
#define RCP(x) __builtin_amdgcn_rcpf(x)
#define L2E 1.44269504089f
#define TWO_L2E 2.88539008177f

// (512,2): proven no-spill point (r8: VGPR=104). (512,4) spills bf[] (r10).
__global__ __launch_bounds__(512, 2)
void lstm_mfma(const float* __restrict__ x,
               const float* __restrict__ W_ih,
               const float* __restrict__ W_hh,
               const float* __restrict__ b_ih,
               const float* __restrict__ b_hh,
               const float* __restrict__ W0,
               const float* __restrict__ b0v,
               const float* __restrict__ W1,
               const float* __restrict__ b1v,
               float* __restrict__ out)
{
  __shared__ __align__(16) _Float16 Hb[2][TB * HROWF];
  __shared__ __align__(16) _Float16 Xp[2][XPANEL];
  __shared__ float y0ls[TB * 132];

  const int tid = threadIdx.x;
  const int bbase = blockIdx.x * TB;
  const int wv = tid >> 6;      // wave 0..7: owns units wv*16 .. wv*16+15 (x4 gates)
  const int lane = tid & 63;
  const int col = lane & 15;    // A-row (sample) / D-col (unit)
  const int grp = lane >> 4;    // k-slot group / D-row block

  // ---- B-fragments (pre-scaled for exp2 gates); lane holds i,f,g,o of unit
  // wv*16+col -> gate math fully lane-local (r8-proven) ----
  half8 bf[4][5];
  float bias[4];
  #pragma unroll
  for (int g = 0; g < 4; ++g) {
    const float sc0 = (g == 2) ? TWO_L2E : L2E;
    const int n = g * 128 + wv * 16 + col;
    #pragma unroll
    for (int ks = 0; ks < 4; ++ks) {
      const float4 p = *reinterpret_cast<const float4*>(W_hh + n * HH + ks * 32 + grp * 8);
      const float4 q = *reinterpret_cast<const float4*>(W_hh + n * HH + ks * 32 + grp * 8 + 4);
      bf[g][ks] = (half8){(_Float16)(p.x * sc0), (_Float16)(p.y * sc0),
                          (_Float16)(p.z * sc0), (_Float16)(p.w * sc0),
                          (_Float16)(q.x * sc0), (_Float16)(q.y * sc0),
                          (_Float16)(q.z * sc0), (_Float16)(q.w * sc0)};
    }
    {
      float v[8];
      #pragma unroll
      for (int j = 0; j < 8; ++j) {
        const int cc = grp * 8 + j;
        v[j] = (cc < II) ? W_ih[n * II + cc] * sc0 : 0.0f;
      }
      bf[g][4] = (half8){(_Float16)v[0], (_Float16)v[1], (_Float16)v[2], (_Float16)v[3],
                         (_Float16)v[4], (_Float16)v[5], (_Float16)v[6], (_Float16)v[7]};
    }
    bias[g] = (b_ih[n] + b_hh[n]) * sc0;
  }

  // ---- x stager: 480 threads x 16 consecutive floats per window (r6-proven) ----
  const bool stg = (tid < 480);
  const int sS = stg ? (tid / 30) : 15;   // sample 0..15
  const int qS = tid % 30;
  const int g0 = qS * 16;                 // 64B-aligned float offset in window
  const int tt0 = g0 / II;
  const int i00 = g0 % II;
  const float* wbase = x + (size_t)(bbase + sS) * (TT * II);

  float4 xr0, xr1, xr2, xr3;
  auto xload = [&](int win) {
    if (!stg) return;
    const float* p = wbase + win * (XTT * II) + g0;
    xr0 = *reinterpret_cast<const float4*>(p);
    xr1 = *reinterpret_cast<const float4*>(p + 4);
    xr2 = *reinterpret_cast<const float4*>(p + 8);
    xr3 = *reinterpret_cast<const float4*>(p + 12);
  };
  auto xwrite = [&](int dstb) {
    if (!stg) return;
    _Float16* d = &Xp[dstb][0];
    const float vv[16] = {xr0.x, xr0.y, xr0.z, xr0.w, xr1.x, xr1.y, xr1.z, xr1.w,
                          xr2.x, xr2.y, xr2.z, xr2.w, xr3.x, xr3.y, xr3.z, xr3.w};
    int tt = tt0, i = i00;
    #pragma unroll
    for (int j = 0; j < 16; ++j) {
      d[tt * (TB * XROWF) + sS * XROWF + i] = (_Float16)vv[j];
      ++i;
      if (i == II) { i = 0; ++tt; }
    }
  };

  // ---- zero Hb (h(0)=0) and Xp (pad cols stay benign) ----
  {
    _Float16* hflat = &Hb[0][0];            // 2*16*136 = 4352 f16
    for (int i8 = tid; i8 < (2 * TB * HROWF) / 8; i8 += 512)
      *reinterpret_cast<half8*>(hflat + i8 * 8) = (half8){0,0,0,0,0,0,0,0};
    _Float16* xflat = &Xp[0][0];            // 2*10240 f16
    for (int i8 = tid; i8 < (2 * XPANEL) / 8; i8 += 512)
      *reinterpret_cast<half8*>(xflat + i8 * 8) = (half8){0,0,0,0,0,0,0,0};
  }

  float c[4] = {0.0f, 0.0f, 0.0f, 0.0f};

  xload(0);
  __syncthreads();   // zero-init visible before window-0 writes
  xwrite(0);
  __syncthreads();

  auto step = [&](int tt_idx, const _Float16* Ar, _Float16* Aw, const _Float16* Xr) {
    half8 af[5];
    #pragma unroll
    for (int ks = 0; ks < 4; ++ks)
      af[ks] = *reinterpret_cast<const half8*>(&Ar[col * HROWF + ks * 32 + grp * 8]);
    af[4] = *reinterpret_cast<const half8*>(&Xr[tt_idx * (TB * XROWF) + col * XROWF + grp * 8]);

    f32x4 a0 = {bias[0], bias[0], bias[0], bias[0]};
    f32x4 a1 = {bias[1], bias[1], bias[1], bias[1]};
    f32x4 a2 = {bias[2], bias[2], bias[2], bias[2]};
    f32x4 a3 = {bias[3], bias[3], bias[3], bias[3]};
    #pragma unroll
    for (int ks = 0; ks < 5; ++ks)
      a0 = __builtin_amdgcn_mfma_f32_16x16x32_f16(af[ks], bf[0][ks], a0, 0, 0, 0);
    #pragma unroll
    for (int ks = 0; ks < 5; ++ks)
      a1 = __builtin_amdgcn_mfma_f32_16x16x32_f16(af[ks], bf[1][ks], a1, 0, 0, 0);
    #pragma unroll
    for (int ks = 0; ks < 5; ++ks)
      a2 = __builtin_amdgcn_mfma_f32_16x16x32_f16(af[ks], bf[2][ks], a2, 0, 0, 0);
    #pragma unroll
    for (int ks = 0; ks < 5; ++ks)
      a3 = __builtin_amdgcn_mfma_f32_16x16x32_f16(af[ks], bf[3][ks], a3, 0, 0, 0);

    // fused gates (r8-proven math), ALL lanes productive: 4 quads/lane,
    // same per-wave issue count as r8's exec-masked version.
    #pragma unroll
    for (int r = 0; r < 4; ++r) {
      const float Ei = EXP2(-a0[r]);
      const float Ef = EXP2(-a1[r]);
      const float Eg = EXP2(fminf(a2[r], 126.0f));
      const float Eo = EXP2(-a3[r]);
      const float ig = (Eg - 1.0f) * RCP((1.0f + Ei) * (Eg + 1.0f));
      const float ff = RCP(1.0f + Ef);
      const float cn = fmaf(ff, c[r], ig);
      c[r] = cn;
      const float Ec = EXP2(fminf(cn * TWO_L2E, 126.0f));
      const float oth = (Ec - 1.0f) * RCP((1.0f + Eo) * (Ec + 1.0f));
      Aw[(grp * 4 + r) * HROWF + wv * 16 + col] = (_Float16)oth;
    }
    __syncthreads();
  };

  // ================= recurrence: 16 windows x 16 steps =================
  for (int win = 0; win < 16; ++win) {
    const _Float16* Xr = &Xp[win & 1][0];
    if (win + 1 < 16) xload(win + 1);
    for (int k = 0; k < 8; k += 2) {
      step(k,     &Hb[0][0], &Hb[1][0], Xr);
      step(k + 1, &Hb[1][0], &Hb[0][0], Xr);
    }
    if (win + 1 < 16) xwrite((win + 1) & 1);   // other buffer: unread this window
    for (int k = 8; k < 16; k += 2) {
      step(k,     &Hb[0][0], &Hb[1][0], Xr);
      step(k + 1, &Hb[1][0], &Hb[0][0], Xr);
    }
  }

  // ================= head =================
  if (tid < TB * 16) {
    const int s = tid >> 4;          // 0..15
    const int n0 = (tid & 15) * 8;
    float acch[8];
    #pragma unroll
    for (int nj = 0; nj < 8; ++nj) acch[nj] = b0v[n0 + nj];
    #pragma unroll
    for (int kb = 0; kb < 16; ++kb) {
      const half8 hh = *reinterpret_cast<const half8*>(&Hb[0][s * HROWF + kb * 8]);
      float hf[8];
      #pragma unroll
      for (int j = 0; j < 8; ++j) hf[j] = (float)hh[j];
      #pragma unroll
      for (int nj = 0; nj < 8; ++nj) {
        const float4 w0 = *reinterpret_cast<const float4*>(W0 + (n0 + nj) * HH + kb * 8);
        const float4 w1 = *reinterpret_cast<const float4*>(W0 + (n0 + nj) * HH + kb * 8 + 4);
        acch[nj] = fmaf(hf[0], w0.x, fmaf(hf[1], w0.y, fmaf(hf[2], w0.z, fmaf(hf[3], w0.w,
                   fmaf(hf[4], w1.x, fmaf(hf[5], w1.y, fmaf(hf[6], w1.z, fmaf(hf[7], w1.w,
                        acch[nj]))))))));
      }
    }
    #pragma unroll
    for (int nj = 0; nj < 8; ++nj)
      y0ls[s * 132 + n0 + nj] = fmaxf(acch[nj], 0.0f);
  }
  __syncthreads();

  if (tid < TB * 11) {
    const int s = tid / 11;
    const int oo = tid % 11;
    float acc1 = b1v[oo];
    const float4* y4 = reinterpret_cast<const float4*>(y0ls + s * 132);
    const float4* w4 = reinterpret_cast<const float4*>(W1 + oo * HH);
    #pragma unroll 8
    for (int k4 = 0; k4 < 32; ++k4) {
      const float4 yv = y4[k4];
      const float4 wv4 = w4[k4];
      acc1 = fmaf(yv.x, wv4.x, fmaf(yv.y, wv4.y, fmaf(yv.z, wv4.z, fmaf(yv.w, wv4.w, acc1))));
    }
    out[(size_t)(bbase + s) * 11 + oo] = acc1;
  }
}

extern "C" void kernel_launch(void* const* d_in, const int* in_sizes, int n_in,
                              void* d_out, int out_size, void* d_ws, size_t ws_size,
                              hipStream_t stream) {
  const float* x    = (const float*)d_in[0];
  const float* W_ih = (const float*)d_in[1];
  const float* W_hh = (const float*)d_in[2];
  const float* b_ih = (const float*)d_in[3];
  const float* b_hh = (const float*)d_in[4];
  const float* W0   = (const float*)d_in[5];
  const float* b0   = (const float*)d_in[6];
  const float* W1   = (const float*)d_in[7];
  const float* b1   = (const float*)d_in[8];
  float* out = (float*)d_out;
  lstm_mfma<<<256, 512, 0, stream>>>(x, W_ih, W_hh, b_ih, b_hh, W0, b0, W1, b1, out);
}